// Round 1
// baseline (418.455 us; speedup 1.0000x reference)
//
#include <hip/hip_runtime.h>
#include <math.h>

#define NJ   16
#define MM   256
#define NINQ 288
#define L2C  1e-4
#define SIGC 0.1
#define NITER 20

__device__ __forceinline__ double wsum(double v) {
#pragma unroll
    for (int off = 32; off > 0; off >>= 1) v += __shfl_down(v, off, 64);
    return v;
}
__device__ __forceinline__ double wmin(double v) {
#pragma unroll
    for (int off = 32; off > 0; off >>= 1) v = fmin(v, __shfl_down(v, off, 64));
    return v;
}

// One block per batch element. 256 threads: thread k <-> flow cell (i = k>>4, j = k&15).
// QP: min 0.5*L2*||x||^2 + p.x  s.t.  -x<=0, rowsum_i(x)<=w1_i, colsum_j(x)<=w2_j, sum(x)=b.
// H = L2*I + G^T diag(d) G = D' + U diag(w) U^T  (D' diag, U = 32 row/col indicators).
// Woodbury + Schur on the 32x32 capacitance matrix -> one 16x16 SPD Cholesky per iter.
__global__ __launch_bounds__(256) void emd_ip_kernel(const float* __restrict__ jets1,
                                                     const float* __restrict__ jets2,
                                                     float* __restrict__ out) {
    const int tid  = threadIdx.x;
    const int b    = blockIdx.x;
    const int i    = tid >> 4;
    const int j    = tid & 15;
    const int lane = tid & 63;
    const int wid  = tid >> 6;

    __shared__ double zt[32];            // z tail (constraints 256..287)
    __shared__ double tt[32];            // t tail
    __shared__ double rsx[16], csx[16];  // row/col sums of x
    __shared__ double invD[256];         // 1/D'_k
    __shared__ double rD1[256];          // r1_k / D'_k
    __shared__ double rsI[16], csI[16];  // row/col sums of invD
    __shared__ double rsR[16], csR[16];  // row/col sums of rD1
    __shared__ double ar[16];            // 1/a_i  (A block inverse diag)
    __shared__ double bbj[16];           // b_j    (B block diag)
    __shared__ double S[16][17];         // Schur complement / its Cholesky factor (lower)
    __shared__ double invdL[16];         // 1/L[k][k]
    __shared__ double qc1[16], qcv[16], qr1[16], qrv[16];
    __shared__ double dxl[256];
    __shared__ double xls[256];
    __shared__ double rsdx[16], csdx[16];
    __shared__ double red[8];
    __shared__ double w1s[16], w2s[16];
    __shared__ double scal[1];           // ra
    __shared__ double sB, sE;            // b_eq, energy_diff

    // ---- load inputs, cost vector p (fp64, matching reference rounding) ----
    const float* p1 = jets1 + b * NJ * 3;
    const float* p2 = jets2 + b * NJ * 3;
    double ax = (double)p1[i * 3 + 0], ay = (double)p1[i * 3 + 1];
    double bx = (double)p2[j * 3 + 0], by = (double)p2[j * 3 + 1];
    double d0 = (bx - ax) + 1e-12;
    double d1 = (by - ay) + 1e-12;
    double px = sqrt(d0 * d0 + d1 * d1);

    if (tid < 16)      w1s[tid]      = (double)p1[tid * 3 + 2];
    else if (tid < 32) w2s[tid - 16] = (double)p2[(tid - 16) * 3 + 2];
    __syncthreads();
    if (tid == 0) {
        double sw1 = 0, sw2 = 0;
        for (int t = 0; t < 16; t++) { sw1 += w1s[t]; sw2 += w2s[t]; }
        sB = fmin(sw1, sw2);
        sE = fabs(sw1 - sw2);
    }

    // ---- state ----
    double xk = 0.0, sk = 1.0, zk = 1.0, yv = 0.0;   // x, s, z (constraint k), y
    double s_t = 1.0, z_t = 1.0, h_t = 0.0;          // tail constraint 256+tid (tid<32)
    if (tid < 32) {
        h_t = (tid < 16) ? w1s[tid] : w2s[tid - 16];
        zt[tid] = 1.0;
    }

    for (int it = 0; it < NITER; ++it) {
        __syncthreads();  // zt / state from previous iteration visible; LDS reuse safe

        // ---- mu = mean(s*z) over 288 ----
        double c = sk * zk;
        if (tid < 32) c += s_t * z_t;
        c = wsum(c);
        if (lane == 0) red[wid] = c;
        __syncthreads();
        double mu = (red[0] + red[1] + red[2] + red[3]) * (1.0 / 288.0);
        __syncthreads();

        // ---- row/col sums of x (for rp tail) ----
        xls[tid] = xk;
        __syncthreads();
        if (tid < 16) {
            double s = 0;
            for (int t = 0; t < 16; t++) s += xls[tid * 16 + t];
            rsx[tid] = s;
        } else if (tid < 32) {
            int jj = tid - 16; double s = 0;
            for (int t = 0; t < 16; t++) s += xls[jj + 16 * t];
            csx[jj] = s;
        }
        __syncthreads();

        // ---- residuals (cell k) ----
        double rxk = L2C * xk + px + (-zk + zt[i] + zt[16 + j]) + yv;
        double rpk = -xk + sk;                    // h_k = 0 for k < 256
        double rsk = sk * zk - SIGC * mu;
        double tk  = (zk * rpk - rsk) / sk;
        double iDk = 1.0 / (L2C + zk / sk);

        // ---- residuals (tail), t tail, ra ----
        double rp_t = 0, rs_t = 0;
        if (tid < 32) {
            rp_t = ((tid < 16) ? rsx[tid] : csx[tid - 16]) + s_t - h_t;
            rs_t = s_t * z_t - SIGC * mu;
            tt[tid] = (z_t * rp_t - rs_t) / s_t;
        }
        if (tid == 32) {
            double s = 0;
            for (int t = 0; t < 16; t++) s += rsx[t];
            scal[0] = s - sB;                     // ra
        }
        __syncthreads();

        // ---- r1 and scaled rhs ----
        double r1k = rxk + (-tk + tt[i] + tt[16 + j]);
        invD[tid] = iDk;
        rD1[tid]  = r1k * iDk;
        __syncthreads();

        // ---- row/col sums of invD and rD1 ----
        if (tid < 16) {
            double s = 0;
            for (int t = 0; t < 16; t++) s += invD[tid * 16 + t];
            rsI[tid] = s;
        } else if (tid < 32) {
            int jj = tid - 16; double s = 0;
            for (int t = 0; t < 16; t++) s += invD[jj + 16 * t];
            csI[jj] = s;
        } else if (tid < 48) {
            int ii = tid - 32; double s = 0;
            for (int t = 0; t < 16; t++) s += rD1[ii * 16 + t];
            rsR[ii] = s;
        } else if (tid < 64) {
            int jj = tid - 48; double s = 0;
            for (int t = 0; t < 16; t++) s += rD1[jj + 16 * t];
            csR[jj] = s;
        }
        __syncthreads();

        // ---- capacitance diag blocks: a_i = 1/dr_i + rowsum(invD), b_j = 1/dc_j + colsum ----
        if (tid < 16) {
            double dr = z_t / s_t;                // d[256+i]
            ar[tid] = 1.0 / (1.0 / dr + rsI[tid]);
        } else if (tid < 32) {
            double dc = z_t / s_t;                // d[272+j]
            bbj[tid - 16] = 1.0 / dc + csI[tid - 16];
        }
        __syncthreads();

        // ---- Schur complement S = B - C^T A^{-1} C  (C[i][j] = invD[i*16+j]) ----
        {
            double acc = 0;
            for (int t = 0; t < 16; t++) acc += invD[t * 16 + i] * invD[t * 16 + j] * ar[t];
            S[i][j] = ((i == j) ? bbj[i] : 0.0) - acc;
        }
        __syncthreads();

        // ---- 16x16 Cholesky (lower), diag kept as 1/L[k][k] in invdL ----
        for (int kk = 0; kk < 16; kk++) {
            if (tid >= kk && tid < 16) {
                double d   = S[kk][kk];
                double inv = 1.0 / sqrt(d);
                if (tid == kk) invdL[kk] = inv;
                else           S[tid][kk] *= inv;   // L[tid][kk]
            }
            __syncthreads();
            if (tid < 16 && tid > kk) {
                double lik = S[tid][kk];
                for (int jj2 = kk + 1; jj2 <= tid; jj2++)
                    S[tid][jj2] -= lik * S[jj2][kk];
            }
            __syncthreads();
        }

        // ---- two RHS solved together in wave 0 (rhs r1 and rhs ones) ----
        if (tid < 16) {
            // gp_c = g_c - C^T A^{-1} g_r
            double g1 = csR[tid], gv = csI[tid];
            for (int t = 0; t < 16; t++) {
                double w = invD[t * 16 + tid] * ar[t];
                g1 -= w * rsR[t];
                gv -= w * rsI[t];
            }
            double y1 = g1, y2 = gv;
            // forward: L y = gp
            for (int kk = 0; kk < 16; kk++) {
                double inv = invdL[kk];
                double t1 = __shfl(y1, kk, 64) * inv;
                double t2 = __shfl(y2, kk, 64) * inv;
                if (tid == kk)      { y1 = t1; y2 = t2; }
                else if (tid > kk)  { double l = S[tid][kk]; y1 -= l * t1; y2 -= l * t2; }
            }
            // backward: L^T q = y
            for (int kk = 15; kk >= 0; kk--) {
                double inv = invdL[kk];
                double t1 = __shfl(y1, kk, 64) * inv;
                double t2 = __shfl(y2, kk, 64) * inv;
                if (tid == kk)      { y1 = t1; y2 = t2; }
                else if (tid < kk)  { double l = S[kk][tid]; y1 -= l * t1; y2 -= l * t2; }
            }
            qc1[tid] = y1;
            qcv[tid] = y2;
        }
        __syncthreads();
        if (tid < 16) {
            // q_r = A^{-1} (g_r - C q_c)
            double a1 = rsR[tid], av = rsI[tid];
            for (int t = 0; t < 16; t++) {
                double cc = invD[tid * 16 + t];
                a1 -= cc * qc1[t];
                av -= cc * qcv[t];
            }
            qr1[tid] = ar[tid] * a1;
            qrv[tid] = ar[tid] * av;
        }
        __syncthreads();

        // ---- u = H^{-1} r1, v = H^{-1} 1 ----
        double uk = (r1k - qr1[i] - qc1[j]) * iDk;
        double vk = (1.0  - qrv[i] - qcv[j]) * iDk;

        double su = wsum(uk), sv = wsum(vk);
        if (lane == 0) { red[wid] = su; red[4 + wid] = sv; }
        __syncthreads();
        double usum = red[0] + red[1] + red[2] + red[3];
        double vsum = red[4] + red[5] + red[6] + red[7];
        double dyv  = (scal[0] - usum) / vsum;
        __syncthreads();

        double dxk = -uk - vk * dyv;
        dxl[tid] = dxk;
        __syncthreads();
        if (tid < 16) {
            double s = 0;
            for (int t = 0; t < 16; t++) s += dxl[tid * 16 + t];
            rsdx[tid] = s;
        } else if (tid < 32) {
            int jj = tid - 16; double s = 0;
            for (int t = 0; t < 16; t++) s += dxl[jj + 16 * t];
            csdx[jj] = s;
        }
        __syncthreads();

        double dsk = -rpk + dxk;                   // ds_k = -rp_k - (dx G^T)_k, (dx G^T)_k = -dx_k
        double dzk = (-rsk - zk * dsk) / sk;

        double am = 1e300;
        if (dsk < 0.0) am = fmin(am, -sk / dsk);
        if (dzk < 0.0) am = fmin(am, -zk / dzk);
        double ds_t = 0, dz_t = 0;
        if (tid < 32) {
            ds_t = -rp_t - ((tid < 16) ? rsdx[tid] : csdx[tid - 16]);
            dz_t = (-rs_t - z_t * ds_t) / s_t;
            if (ds_t < 0.0) am = fmin(am, -s_t / ds_t);
            if (dz_t < 0.0) am = fmin(am, -z_t / dz_t);
        }
        am = wmin(am);
        if (lane == 0) red[wid] = am;
        __syncthreads();
        double amin  = fmin(fmin(red[0], red[1]), fmin(red[2], red[3]));
        double alpha = 0.99 * fmin(1.0, amin);

        // ---- step ----
        xk += alpha * dxk;
        sk += alpha * dsk;
        zk += alpha * dzk;
        yv += alpha * dyv;
        if (tid < 32) {
            s_t += alpha * ds_t;
            z_t += alpha * dz_t;
            zt[tid] = z_t;
        }
    }

    // ---- emd = p.x + |sum w1 - sum w2| ----
    __syncthreads();
    double e = wsum(px * xk);
    if (lane == 0) red[wid] = e;
    __syncthreads();
    if (tid == 0) out[b] = (float)(red[0] + red[1] + red[2] + red[3] + sE);
}

extern "C" void kernel_launch(void* const* d_in, const int* in_sizes, int n_in,
                              void* d_out, int out_size, void* d_ws, size_t ws_size,
                              hipStream_t stream) {
    const float* jets1 = (const float*)d_in[0];
    const float* jets2 = (const float*)d_in[1];
    float* out = (float*)d_out;
    int B = in_sizes[0] / (NJ * 3);   // 32
    emd_ip_kernel<<<dim3(B), dim3(256), 0, stream>>>(jets1, jets2, out);
}

// Round 2
// 335.654 us; speedup vs baseline: 1.2467x; 1.2467x over previous
//
#include <hip/hip_runtime.h>
#include <math.h>

#define L2C  1e-4
#define SIGC 0.1
#define NITER 20

// full-wave butterfly sum / min (all lanes end with the total)
__device__ __forceinline__ double bsum(double v) {
#pragma unroll
    for (int off = 1; off < 64; off <<= 1) v += __shfl_xor(v, off, 64);
    return v;
}
__device__ __forceinline__ double bmin(double v) {
#pragma unroll
    for (int off = 1; off < 64; off <<= 1) v = fmin(v, __shfl_xor(v, off, 64));
    return v;
}

// One 64-lane wave per batch element. Lane l owns 4 flow cells:
//   i = l>>2, j = 4*(l&3)+c  (c = 0..3), flat k = 4*l+c.
// Tail constraint roles: lane t<16 = row-tail t, lane 16+j = col-tail j.
// S-matrix roles: lane r<16 holds row r of the 16x16 Schur complement in REGISTERS.
// Woodbury + Schur: H = D' + U diag(w) U^T -> one register-resident 16x16 Cholesky
// + shuffle-based triangular solves. LDS only holds invD (transposed access);
// exactly one __syncthreads per iteration (single-wave barrier, ~free).
__global__ __launch_bounds__(64) void emd_ip_kernel(const float* __restrict__ jets1,
                                                    const float* __restrict__ jets2,
                                                    float* __restrict__ out) {
    const int l  = threadIdx.x;
    const int b  = blockIdx.x;
    const int i  = l >> 2;
    const int jq = l & 3;
    const int tj = (l - 16) & 15;   // tail-col index for lanes 16..31

    __shared__ double invDl[256];

    const float* p1 = jets1 + b * 48;
    const float* p2 = jets2 + b * 48;

    double ax = (double)p1[3 * i], ay = (double)p1[3 * i + 1];
    double px[4];
#pragma unroll
    for (int c = 0; c < 4; c++) {
        int j = 4 * jq + c;
        double d0 = ((double)p2[3 * j]     - ax) + 1e-12;
        double d1 = ((double)p2[3 * j + 1] - ay) + 1e-12;
        px[c] = sqrt(d0 * d0 + d1 * d1);
    }
    double wv = 0.0;
    if (l < 16)      wv = (double)p1[3 * l + 2];
    else if (l < 32) wv = (double)p2[3 * (l - 16) + 2];
    double va = (l < 16) ? wv : 0.0;
    double vb = (l >= 16 && l < 32) ? wv : 0.0;
#pragma unroll
    for (int off = 1; off < 64; off <<= 1) {
        va += __shfl_xor(va, off, 64);
        vb += __shfl_xor(vb, off, 64);
    }
    const double sB = fmin(va, vb);     // b_eq
    const double sE = fabs(va - vb);    // energy diff
    const double h_t = wv;              // tail bound (0 for l>=32)

    double x[4] = {0, 0, 0, 0}, s[4] = {1, 1, 1, 1}, z[4] = {1, 1, 1, 1};
    double y = 0.0;
    double s_t = 1.0, z_t = 1.0;        // tail slack/dual (lanes < 32)

    for (int it = 0; it < NITER; ++it) {
        // ---- mu = mean(s*z) over 288 ----
        double c288 = s[0] * z[0] + s[1] * z[1] + s[2] * z[2] + s[3] * z[3];
        if (l < 32) c288 += s_t * z_t;
        double mu = bsum(c288) * (1.0 / 288.0);

        // ---- row/col/total sums of x ----
        double lx = x[0] + x[1] + x[2] + x[3];
        double rsx = lx + __shfl_xor(lx, 1, 64);
        rsx += __shfl_xor(rsx, 2, 64);                       // row sum (4 lanes/row)
        double txs = rsx + __shfl_xor(rsx, 4, 64);
        txs += __shfl_xor(txs, 8, 64);
        txs += __shfl_xor(txs, 16, 64);
        txs += __shfl_xor(txs, 32, 64);                      // total sum(x)
        double cs[4];
#pragma unroll
        for (int c = 0; c < 4; c++) {
            double v = x[c];
            v += __shfl_xor(v, 4, 64);
            v += __shfl_xor(v, 8, 64);
            v += __shfl_xor(v, 16, 64);
            v += __shfl_xor(v, 32, 64);                      // col sum of col 4*jq+c
            cs[c] = v;
        }
        double ra = txs - sB;

        // tail gathers
        double rsx_t = __shfl(rsx, 4 * (l & 15), 64);
        double g0 = __shfl(cs[0], tj >> 2, 64);
        double g1 = __shfl(cs[1], tj >> 2, 64);
        double g2 = __shfl(cs[2], tj >> 2, 64);
        double g3 = __shfl(cs[3], tj >> 2, 64);
        int sel = tj & 3;
        double csx_t = (sel == 0) ? g0 : (sel == 1) ? g1 : (sel == 2) ? g2 : g3;
        double rc = (l < 16) ? rsx_t : csx_t;

        // ---- tail residuals ----
        double rp_t = rc + s_t - h_t;
        double rs_t = s_t * z_t - SIGC * mu;
        double tt   = (z_t * rp_t - rs_t) / s_t;

        // ---- cell residuals ----
        double ztr = __shfl(z_t, i, 64);
        double ttr = __shfl(tt, i, 64);
        double rp[4], rs[4], iD[4], r1[4];
#pragma unroll
        for (int c = 0; c < 4; c++) {
            double ztc = __shfl(z_t, 16 + 4 * jq + c, 64);
            double ttc = __shfl(tt,  16 + 4 * jq + c, 64);
            double rx = L2C * x[c] + px[c] + (-z[c] + ztr + ztc) + y;
            rp[c] = s[c] - x[c];
            rs[c] = s[c] * z[c] - SIGC * mu;
            double tk = (z[c] * rp[c] - rs[c]) / s[c];
            iD[c] = 1.0 / (L2C + z[c] / s[c]);
            r1[c] = rx - tk + ttr + ttc;
        }

        // ---- stage invD to LDS (transposed access needed later) ----
#pragma unroll
        for (int c = 0; c < 4; c++) invDl[4 * l + c] = iD[c];
        __syncthreads();   // single-wave barrier: ~free

        // ---- row/col sums of invD and rD1 = r1*invD ----
        double rD1[4];
#pragma unroll
        for (int c = 0; c < 4; c++) rD1[c] = r1[c] * iD[c];
        double li = iD[0] + iD[1] + iD[2] + iD[3];
        double rsI = li + __shfl_xor(li, 1, 64);  rsI += __shfl_xor(rsI, 2, 64);
        double lr = rD1[0] + rD1[1] + rD1[2] + rD1[3];
        double rsR = lr + __shfl_xor(lr, 1, 64);  rsR += __shfl_xor(rsR, 2, 64);
        double csI[4], csR[4];
#pragma unroll
        for (int c = 0; c < 4; c++) {
            double v = iD[c];
            v += __shfl_xor(v, 4, 64); v += __shfl_xor(v, 8, 64);
            v += __shfl_xor(v, 16, 64); v += __shfl_xor(v, 32, 64);
            csI[c] = v;
            double w = rD1[c];
            w += __shfl_xor(w, 4, 64); w += __shfl_xor(w, 8, 64);
            w += __shfl_xor(w, 16, 64); w += __shfl_xor(w, 32, 64);
            csR[c] = w;
        }
        // tail-indexed gathers
        double rsI_t = __shfl(rsI, 4 * (l & 15), 64);
        double rsR_t = __shfl(rsR, 4 * (l & 15), 64);
        double h0 = __shfl(csI[0], tj >> 2, 64), h1 = __shfl(csI[1], tj >> 2, 64);
        double h2 = __shfl(csI[2], tj >> 2, 64), h3 = __shfl(csI[3], tj >> 2, 64);
        double csI_t = (sel == 0) ? h0 : (sel == 1) ? h1 : (sel == 2) ? h2 : h3;
        double k0 = __shfl(csR[0], tj >> 2, 64), k1 = __shfl(csR[1], tj >> 2, 64);
        double k2 = __shfl(csR[2], tj >> 2, 64), k3 = __shfl(csR[3], tj >> 2, 64);
        double csR_t = (sel == 0) ? k0 : (sel == 1) ? k1 : (sel == 2) ? k2 : k3;

        // capacitance diagonal: lanes<16 hold ar_t = 1/A_t, lanes 16..31 hold B_j
        double sz = s_t / z_t;   // 1/d_tail
        double capv = (l < 16) ? 1.0 / (sz + rsI_t) : (sz + csI_t);

        // ---- Schur complement S = B - C^T A^{-1} C  (4 outputs per lane) ----
        double bbi = __shfl(capv, 16 + i, 64);
        double acc[4] = {0, 0, 0, 0};
#pragma unroll
        for (int t = 0; t < 16; t++) {
            double art = __shfl(capv, t, 64);
            double w = art * invDl[t * 16 + i];
#pragma unroll
            for (int c = 0; c < 4; c++) acc[c] += w * invDl[t * 16 + 4 * jq + c];
        }
        double Sc[4];
#pragma unroll
        for (int c = 0; c < 4; c++) {
            int j = 4 * jq + c;
            Sc[c] = ((i == j) ? bbi : 0.0) - acc[c];
        }

        // ---- gather S row r into registers of lane r (r<16) ----
        double Sr[16];
#pragma unroll
        for (int jj = 0; jj < 16; jj++)
            Sr[jj] = __shfl(Sc[jj & 3], 4 * (l & 15) + (jj >> 2), 64);

        // ---- register-resident 16x16 Cholesky (lower), record L^T rows ----
        double LT[16];
#pragma unroll
        for (int q = 0; q < 16; q++) LT[q] = 0.0;
        double invdv = 0.0;
#pragma unroll
        for (int kk = 0; kk < 16; kk++) {
            double dkk = __shfl(Sr[kk], kk, 64);
            double inv = 1.0 / sqrt(dkk);
            if (l == kk) invdv = inv;
            double Lc = Sr[kk] * inv;      // L[l][kk] for l>=kk
            Sr[kk] = Lc;
#pragma unroll
            for (int jj = kk; jj < 16; jj++) {
                double lj = __shfl(Lc, jj, 64);    // L[jj][kk]
                if (l == kk) LT[jj] = lj;          // lane r records column r as LT row
                if (jj > kk && l >= jj) Sr[jj] -= Lc * lj;
            }
        }

        // ---- rhs: gp = csX - C^T A^{-1} rsX  (2 rhs fused: r1-solve and ones-solve) ----
        double wR = capv * rsR_t;     // lanes<16: ar_t * rsR_t
        double wI = capv * rsI_t;
        double y1 = __shfl(csR_t, 16 + (l & 15), 64);
        double y2 = __shfl(csI_t, 16 + (l & 15), 64);
#pragma unroll
        for (int t = 0; t < 16; t++) {
            double wr = __shfl(wR, t, 64);
            double wi = __shfl(wI, t, 64);
            double cti = invDl[t * 16 + (l & 15)];
            y1 -= cti * wr;
            y2 -= cti * wi;
        }

        // ---- forward solve L y = gp ----
#pragma unroll
        for (int kk = 0; kk < 16; kk++) {
            double inv = __shfl(invdv, kk, 64);
            double t1 = __shfl(y1, kk, 64) * inv;
            double t2 = __shfl(y2, kk, 64) * inv;
            if (l == kk)      { y1 = t1; y2 = t2; }
            else if (l > kk)  { y1 -= Sr[kk] * t1; y2 -= Sr[kk] * t2; }
        }
        // ---- backward solve L^T q = y ----
#pragma unroll
        for (int kk = 15; kk >= 0; kk--) {
            double inv = __shfl(invdv, kk, 64);
            double t1 = __shfl(y1, kk, 64) * inv;
            double t2 = __shfl(y2, kk, 64) * inv;
            if (l == kk)      { y1 = t1; y2 = t2; }
            else if (l < kk)  { y1 -= LT[kk] * t1; y2 -= LT[kk] * t2; }
        }
        // y1,y2 now = qc (col-block solution) at lanes 0..15

        // ---- qr = A^{-1} (rsX - C qc) at lanes 0..15 ----
        double a1 = rsR_t, av = rsI_t;
#pragma unroll
        for (int t = 0; t < 16; t++) {
            double q1t = __shfl(y1, t, 64);
            double q2t = __shfl(y2, t, 64);
            double ct = invDl[(l & 15) * 16 + t];
            a1 -= ct * q1t;
            av -= ct * q2t;
        }
        double qr1 = capv * a1;
        double qrv = capv * av;

        // ---- u = H^{-1} r1, v = H^{-1} 1 (all 64 lanes, 4 cells each) ----
        double qri  = __shfl(qr1, i, 64);
        double qrvi = __shfl(qrv, i, 64);
        double u[4], v[4];
        double su = 0, sv = 0;
#pragma unroll
        for (int c = 0; c < 4; c++) {
            double qc1c = __shfl(y1, 4 * jq + c, 64);
            double qcvc = __shfl(y2, 4 * jq + c, 64);
            u[c] = (r1[c] - qri - qc1c) * iD[c];
            v[c] = (1.0   - qrvi - qcvc) * iD[c];
            su += u[c]; sv += v[c];
        }
        double usum = su, vsum = sv;
#pragma unroll
        for (int off = 1; off < 64; off <<= 1) {
            usum += __shfl_xor(usum, off, 64);
            vsum += __shfl_xor(vsum, off, 64);
        }
        double dy = (ra - usum) / vsum;

        // ---- dx and its row/col sums ----
        double dx[4];
#pragma unroll
        for (int c = 0; c < 4; c++) dx[c] = -u[c] - v[c] * dy;
        double ldx = dx[0] + dx[1] + dx[2] + dx[3];
        double rsdx = ldx + __shfl_xor(ldx, 1, 64);
        rsdx += __shfl_xor(rsdx, 2, 64);
        double csdx[4];
#pragma unroll
        for (int c = 0; c < 4; c++) {
            double w = dx[c];
            w += __shfl_xor(w, 4, 64); w += __shfl_xor(w, 8, 64);
            w += __shfl_xor(w, 16, 64); w += __shfl_xor(w, 32, 64);
            csdx[c] = w;
        }
        double rsdx_t = __shfl(rsdx, 4 * (l & 15), 64);
        double m0 = __shfl(csdx[0], tj >> 2, 64), m1 = __shfl(csdx[1], tj >> 2, 64);
        double m2 = __shfl(csdx[2], tj >> 2, 64), m3 = __shfl(csdx[3], tj >> 2, 64);
        double csdx_t = (sel == 0) ? m0 : (sel == 1) ? m1 : (sel == 2) ? m2 : m3;
        double rcdx = (l < 16) ? rsdx_t : csdx_t;

        // ---- ds, dz, step length ----
        double am = 1e300;
        double ds[4], dz[4];
#pragma unroll
        for (int c = 0; c < 4; c++) {
            ds[c] = dx[c] - rp[c];
            dz[c] = (-rs[c] - z[c] * ds[c]) / s[c];
            if (ds[c] < 0.0) am = fmin(am, -s[c] / ds[c]);
            if (dz[c] < 0.0) am = fmin(am, -z[c] / dz[c]);
        }
        double ds_t = 0.0, dz_t = 0.0;
        if (l < 32) {
            ds_t = -rp_t - rcdx;
            dz_t = (-rs_t - z_t * ds_t) / s_t;
            if (ds_t < 0.0) am = fmin(am, -s_t / ds_t);
            if (dz_t < 0.0) am = fmin(am, -z_t / dz_t);
        }
        double amin = bmin(am);
        double alpha = 0.99 * fmin(1.0, amin);

        // ---- step ----
#pragma unroll
        for (int c = 0; c < 4; c++) {
            x[c] += alpha * dx[c];
            s[c] += alpha * ds[c];
            z[c] += alpha * dz[c];
        }
        y += alpha * dy;
        if (l < 32) {
            s_t += alpha * ds_t;
            z_t += alpha * dz_t;
        }
        __syncthreads();   // protect invDl reuse next iteration (single-wave: ~free)
    }

    // ---- emd = p.x + |sum w1 - sum w2| ----
    double e = px[0] * x[0] + px[1] * x[1] + px[2] * x[2] + px[3] * x[3];
    e = bsum(e);
    if (l == 0) out[b] = (float)(e + sE);
}

extern "C" void kernel_launch(void* const* d_in, const int* in_sizes, int n_in,
                              void* d_out, int out_size, void* d_ws, size_t ws_size,
                              hipStream_t stream) {
    const float* jets1 = (const float*)d_in[0];
    const float* jets2 = (const float*)d_in[1];
    float* out = (float*)d_out;
    int B = in_sizes[0] / 48;   // 32
    emd_ip_kernel<<<dim3(B), dim3(64), 0, stream>>>(jets1, jets2, out);
}

// Round 3
// 218.705 us; speedup vs baseline: 1.9133x; 1.5347x over previous
//
#include <hip/hip_runtime.h>
#include <math.h>

#define L2C  1e-4
#define SIGC 0.1
#define NITER 20

// ---- cross-lane helpers ---------------------------------------------------
// readlane broadcast of a double from a compile-time-constant lane (no DS).
__device__ __forceinline__ double rl(double v, int lane) {
    union { double d; int i[2]; } u, r;
    u.d = v;
    r.i[0] = __builtin_amdgcn_readlane(u.i[0], lane);
    r.i[1] = __builtin_amdgcn_readlane(u.i[1], lane);
    return r.d;
}
// DPP move of a double (VALU, no DS). CTRL: 0xB1=xor1, 0x4E=xor2, 0x124=ror4, 0x128=ror8.
template <int CTRL>
__device__ __forceinline__ double dppd(double v) {
    union { double d; int i[2]; } u, r;
    u.d = v;
    r.i[0] = __builtin_amdgcn_update_dpp(0, u.i[0], CTRL, 0xF, 0xF, true);
    r.i[1] = __builtin_amdgcn_update_dpp(0, u.i[1], CTRL, 0xF, 0xF, true);
    return r.d;
}
// full reduction across a 16-lane row (every lane gets the total) — all VALU.
__device__ __forceinline__ double sum16(double v) {
    v += dppd<0xB1>(v);          // xor1 (quad_perm [1,0,3,2])
    v += dppd<0x4E>(v);          // xor2 (quad_perm [2,3,0,1])
    v += dppd<0x124>(v);         // row_ror:4
    v += dppd<0x128>(v);         // row_ror:8
    return v;
}
__device__ __forceinline__ double min16(double v) {
    v = fmin(v, dppd<0xB1>(v));
    v = fmin(v, dppd<0x4E>(v));
    v = fmin(v, dppd<0x124>(v));
    v = fmin(v, dppd<0x128>(v));
    return v;
}
// combine the 4 rows-of-16 (butterfly -> bit-identical across rows)
__device__ __forceinline__ double cross4(double v) {
    v += __shfl_xor(v, 16, 64);
    v += __shfl_xor(v, 32, 64);
    return v;
}
__device__ __forceinline__ double cross4min(double v) {
    v = fmin(v, __shfl_xor(v, 16, 64));
    v = fmin(v, __shfl_xor(v, 32, 64));
    return v;
}

// One 64-lane wave per batch element.
// Lane l: q = l&15 (owns flow row q), r = l>>4; owns cells (q, 4c+r), c=0..3.
// Row-tail state for row q and col-tail state for cols 4c+r are maintained
// REDUNDANTLY per lane (copies bit-identical / 1-ulp consistent), so residuals
// need zero communication. Woodbury+Schur -> 16x16 Cholesky done entirely in
// registers with v_readlane broadcasts (no DS); reductions via DPP.
__global__ __launch_bounds__(64, 1) void emd_ip_kernel(const float* __restrict__ jets1,
                                                       const float* __restrict__ jets2,
                                                       float* __restrict__ out) {
    const int l = threadIdx.x;
    const int b = blockIdx.x;
    const int q = l & 15;
    const int r = l >> 4;

    __shared__ double invDl[16 * 17];   // [i][j] at i*17+j (pad 17: conflict-free)

    const float* p1 = jets1 + b * 48;
    const float* p2 = jets2 + b * 48;

    double ax = (double)p1[3 * q], ay = (double)p1[3 * q + 1];
    double px[4];
#pragma unroll
    for (int c = 0; c < 4; c++) {
        int j = 4 * c + r;
        double d0 = ((double)p2[3 * j]     - ax) + 1e-12;
        double d1 = ((double)p2[3 * j + 1] - ay) + 1e-12;
        px[c] = sqrt(d0 * d0 + d1 * d1);
    }
    double h_rt = (double)p1[3 * q + 2];          // w1[q]
    double h_ct[4];
#pragma unroll
    for (int c = 0; c < 4; c++) h_ct[c] = (double)p2[3 * (4 * c + r) + 2];  // w2[4c+r]

    double sw1 = sum16(h_rt);
    double sw2 = sum16((double)p2[3 * q + 2]);
    const double sB = fmin(sw1, sw2);
    const double sE = fabs(sw1 - sw2);

    double x[4] = {0, 0, 0, 0}, s[4] = {1, 1, 1, 1}, z[4] = {1, 1, 1, 1};
    double yv = 0.0;
    double s_rt = 1.0, z_rt = 1.0;
    double s_ct[4] = {1, 1, 1, 1}, z_ct[4] = {1, 1, 1, 1};

    for (int it = 0; it < NITER; ++it) {
        // ---- mu = mean(s*z) over 288 (tail copies scaled by redundancy) ----
        double mub = s[0]*z[0] + s[1]*z[1] + s[2]*z[2] + s[3]*z[3]
                   + 0.25 * (s_rt * z_rt)
                   + 0.0625 * (s_ct[0]*z_ct[0] + s_ct[1]*z_ct[1] + s_ct[2]*z_ct[2] + s_ct[3]*z_ct[3]);
        double mu = sum16(cross4(mub)) * (1.0 / 288.0);

        // ---- x sums ----
        double rsx = cross4(x[0] + x[1] + x[2] + x[3]);   // row q sum (exact across copies)
        double txs = sum16(rsx);                          // total
        double cs[4];
#pragma unroll
        for (int c = 0; c < 4; c++) cs[c] = sum16(x[c]);  // col 4c+r sums
        double ra = txs - sB;

        // ---- tail residuals (lane-local, redundant) ----
        double rp_rt = rsx + s_rt - h_rt;
        double rs_rt = s_rt * z_rt - SIGC * mu;
        double tt_rt = (z_rt * rp_rt - rs_rt) / s_rt;
        double rp_ct[4], rs_ct[4], tt_ct[4];
#pragma unroll
        for (int c = 0; c < 4; c++) {
            rp_ct[c] = cs[c] + s_ct[c] - h_ct[c];
            rs_ct[c] = s_ct[c] * z_ct[c] - SIGC * mu;
            tt_ct[c] = (z_ct[c] * rp_ct[c] - rs_ct[c]) / s_ct[c];
        }

        // ---- cell residuals (zero communication) ----
        double rp[4], rs[4], iD[4], r1[4], rD1[4];
#pragma unroll
        for (int c = 0; c < 4; c++) {
            double rx = L2C * x[c] + px[c] + (-z[c] + z_rt + z_ct[c]) + yv;
            rp[c] = s[c] - x[c];
            rs[c] = s[c] * z[c] - SIGC * mu;
            double tk = (z[c] * rp[c] - rs[c]) / s[c];
            iD[c] = 1.0 / (L2C + z[c] / s[c]);
            r1[c] = rx - tk + tt_rt + tt_ct[c];
            rD1[c] = r1[c] * iD[c];
        }

        // ---- stage invD to LDS (transposed access for Schur/rhs/qr) ----
#pragma unroll
        for (int c = 0; c < 4; c++) invDl[q * 17 + 4 * c + r] = iD[c];
        __syncthreads();

        // ---- sums of invD and rD1 ----
        double rsI = cross4(iD[0] + iD[1] + iD[2] + iD[3]);
        double rsR = cross4(rD1[0] + rD1[1] + rD1[2] + rD1[3]);
        double csI[4], csR[4];
#pragma unroll
        for (int c = 0; c < 4; c++) { csI[c] = sum16(iD[c]); csR[c] = sum16(rD1[c]); }

        double ar = 1.0 / (s_rt / z_rt + rsI);   // 1/A_q
        double aR = ar * rsR;
        double aI = ar * rsI;
        double bb[4];
#pragma unroll
        for (int c = 0; c < 4; c++) bb[c] = s_ct[c] / z_ct[c] + csI[c];   // B_{4c+r}

        // ---- Schur S = B - C^T A^{-1} C  and rhs gp = g_c - C^T A^{-1} g_r ----
        double accS[4] = {0, 0, 0, 0}, accR[4] = {0, 0, 0, 0}, accI[4] = {0, 0, 0, 0};
#pragma unroll
        for (int i = 0; i < 16; i++) {
            double sar = rl(ar, i);
            double saR = rl(aR, i);
            double saI = rl(aI, i);
            double ciq = invDl[i * 17 + q];
            double wS = sar * ciq;
#pragma unroll
            for (int c = 0; c < 4; c++) {
                double cij = invDl[i * 17 + 4 * c + r];
                accS[c] += wS * cij;
                accR[c] += saR * cij;
                accI[c] += saI * cij;
            }
        }
        double Sc4[4], gpR[4], gpI[4];
#pragma unroll
        for (int c = 0; c < 4; c++) {
            Sc4[c] = ((q == 4 * c + r) ? bb[c] : 0.0) - accS[c];  // S[q][4c+r]
            gpR[c] = csR[c] - accR[c];                            // gp[4c+r] (r1 rhs)
            gpI[c] = csI[c] - accI[c];                            // gp[4c+r] (ones rhs)
        }

        // ---- gather full S row q into registers (every lane; identical across r) ----
        double Sr[16];
#pragma unroll
        for (int j2 = 0; j2 < 16; j2++)
            Sr[j2] = __shfl(Sc4[j2 >> 2], ((j2 & 3) << 4) + q, 64);

        // ---- register 16x16 Cholesky, readlane broadcasts (no DS) ----
        double LT[16];
#pragma unroll
        for (int t = 0; t < 16; t++) LT[t] = 0.0;
        double invdv = 0.0;
#pragma unroll
        for (int kk = 0; kk < 16; kk++) {
            double dkk = rl(Sr[kk], kk);
            double inv = rsqrt(dkk);
            invdv = (q == kk) ? inv : invdv;
            double Lc = Sr[kk] * inv;     // L[q][kk] (valid for q>=kk)
            Sr[kk] = Lc;
#pragma unroll
            for (int jj = kk + 1; jj < 16; jj++) {
                double lj = rl(Lc, jj);               // L[jj][kk]
                LT[jj] = (q == kk) ? lj : LT[jj];     // lane q records L[m][q]
                Sr[jj] -= Lc * lj;
            }
        }

        // ---- rhs gather: y = gp[q] (4 bpermutes + register select) ----
        double Y0 = __shfl(gpR[0], ((q & 3) << 4) + q, 64);
        double Y1 = __shfl(gpR[1], ((q & 3) << 4) + q, 64);
        double Y2 = __shfl(gpR[2], ((q & 3) << 4) + q, 64);
        double Y3 = __shfl(gpR[3], ((q & 3) << 4) + q, 64);
        double Z0 = __shfl(gpI[0], ((q & 3) << 4) + q, 64);
        double Z1 = __shfl(gpI[1], ((q & 3) << 4) + q, 64);
        double Z2 = __shfl(gpI[2], ((q & 3) << 4) + q, 64);
        double Z3 = __shfl(gpI[3], ((q & 3) << 4) + q, 64);
        int qh = q >> 2;
        double y1 = (qh == 0) ? Y0 : (qh == 1) ? Y1 : (qh == 2) ? Y2 : Y3;
        double y2 = (qh == 0) ? Z0 : (qh == 1) ? Z1 : (qh == 2) ? Z2 : Z3;

        // ---- forward solve L y = gp (readlane, no DS) ----
#pragma unroll
        for (int kk = 0; kk < 16; kk++) {
            double inv = rl(invdv, kk);
            double t1 = rl(y1, kk) * inv;
            double t2 = rl(y2, kk) * inv;
            if (q == kk)      { y1 = t1; y2 = t2; }
            else if (q > kk)  { y1 -= Sr[kk] * t1; y2 -= Sr[kk] * t2; }
        }
        // ---- backward solve L^T qc = y ----
#pragma unroll
        for (int kk = 15; kk >= 0; kk--) {
            double inv = rl(invdv, kk);
            double t1 = rl(y1, kk) * inv;
            double t2 = rl(y2, kk) * inv;
            if (q == kk)      { y1 = t1; y2 = t2; }
            else if (q < kk)  { y1 -= LT[kk] * t1; y2 -= LT[kk] * t2; }
        }
        // y1,y2 = qc[q] on every lane

        // ---- qr = A^{-1}(g_r - C qc) (lane-local for own q) ----
        double a1 = rsR, av = rsI;
#pragma unroll
        for (int jj = 0; jj < 16; jj++) {
            double q1 = rl(y1, jj);
            double q2 = rl(y2, jj);
            double ct = invDl[q * 17 + jj];
            a1 -= ct * q1;
            av -= ct * q2;
        }
        double qr1 = ar * a1, qrv = ar * av;

        // ---- u = H^{-1} r1, v = H^{-1} 1 ----
        double u[4], v[4];
#pragma unroll
        for (int c = 0; c < 4; c++) {
            double qc1c = __shfl(y1, 4 * c + r, 64);
            double qcvc = __shfl(y2, 4 * c + r, 64);
            u[c] = (r1[c] - qr1 - qc1c) * iD[c];
            v[c] = (1.0   - qrv - qcvc) * iD[c];
        }
        double usum = sum16(cross4(u[0] + u[1] + u[2] + u[3]));
        double vsum = sum16(cross4(v[0] + v[1] + v[2] + v[3]));
        double dy = (ra - usum) / vsum;

        // ---- dx and its row/col sums ----
        double dx[4];
#pragma unroll
        for (int c = 0; c < 4; c++) dx[c] = -u[c] - v[c] * dy;
        double rsdx = cross4(dx[0] + dx[1] + dx[2] + dx[3]);
        double csdx[4];
#pragma unroll
        for (int c = 0; c < 4; c++) csdx[c] = sum16(dx[c]);

        // ---- ds, dz, step length ----
        double am = 1e300;
        double ds[4], dz[4];
#pragma unroll
        for (int c = 0; c < 4; c++) {
            ds[c] = dx[c] - rp[c];
            dz[c] = (-rs[c] - z[c] * ds[c]) / s[c];
            if (ds[c] < 0.0) am = fmin(am, -s[c] / ds[c]);
            if (dz[c] < 0.0) am = fmin(am, -z[c] / dz[c]);
        }
        double ds_rt = -rp_rt - rsdx;
        double dz_rt = (-rs_rt - z_rt * ds_rt) / s_rt;
        if (ds_rt < 0.0) am = fmin(am, -s_rt / ds_rt);
        if (dz_rt < 0.0) am = fmin(am, -z_rt / dz_rt);
        double ds_ct[4], dz_ct[4];
#pragma unroll
        for (int c = 0; c < 4; c++) {
            ds_ct[c] = -rp_ct[c] - csdx[c];
            dz_ct[c] = (-rs_ct[c] - z_ct[c] * ds_ct[c]) / s_ct[c];
            if (ds_ct[c] < 0.0) am = fmin(am, -s_ct[c] / ds_ct[c]);
            if (dz_ct[c] < 0.0) am = fmin(am, -z_ct[c] / dz_ct[c]);
        }
        double alpha = 0.99 * fmin(1.0, min16(cross4min(am)));

        // ---- step ----
#pragma unroll
        for (int c = 0; c < 4; c++) {
            x[c] += alpha * dx[c];
            s[c] += alpha * ds[c];
            z[c] += alpha * dz[c];
            s_ct[c] += alpha * ds_ct[c];
            z_ct[c] += alpha * dz_ct[c];
        }
        yv += alpha * dy;
        s_rt += alpha * ds_rt;
        z_rt += alpha * dz_rt;
        __syncthreads();   // protect invDl reuse (single-wave: cheap)
    }

    // ---- emd = p.x + |sum w1 - sum w2| ----
    double e = sum16(cross4(px[0] * x[0] + px[1] * x[1] + px[2] * x[2] + px[3] * x[3]));
    if (l == 0) out[b] = (float)(e + sE);
}

extern "C" void kernel_launch(void* const* d_in, const int* in_sizes, int n_in,
                              void* d_out, int out_size, void* d_ws, size_t ws_size,
                              hipStream_t stream) {
    const float* jets1 = (const float*)d_in[0];
    const float* jets2 = (const float*)d_in[1];
    float* out = (float*)d_out;
    int B = in_sizes[0] / 48;   // 32
    emd_ip_kernel<<<dim3(B), dim3(64), 0, stream>>>(jets1, jets2, out);
}

// Round 6
// 168.350 us; speedup vs baseline: 2.4856x; 1.2991x over previous
//
#include <hip/hip_runtime.h>
#include <math.h>

#define L2C  1e-4
#define SIGC 0.1
#define NITER 20

// ---- cross-lane helpers ----------------------------------------------------
__device__ __forceinline__ double rld(double v, int lane) {
    union { double d; int i[2]; } u, r; u.d = v;
    r.i[0] = __builtin_amdgcn_readlane(u.i[0], lane);
    r.i[1] = __builtin_amdgcn_readlane(u.i[1], lane);
    return r.d;
}
template <int CTRL>
__device__ __forceinline__ double dppd(double v) {
    union { double d; int i[2]; } u, r; u.d = v;
    r.i[0] = __builtin_amdgcn_update_dpp(0, u.i[0], CTRL, 0xF, 0xF, true);
    r.i[1] = __builtin_amdgcn_update_dpp(0, u.i[1], CTRL, 0xF, 0xF, true);
    return r.d;
}
// sum across each 16-lane DPP row (all lanes get the row total)
__device__ __forceinline__ double sum16d(double v) {
    v += dppd<0xB1>(v); v += dppd<0x4E>(v); v += dppd<0x124>(v); v += dppd<0x128>(v);
    return v;
}
// combine the 4 16-lane rows (butterfly -> bit-identical everywhere)
__device__ __forceinline__ double cross4d(double v) {
    v += __shfl_xor(v, 16, 64); v += __shfl_xor(v, 32, 64); return v;
}
template <int CTRL>
__device__ __forceinline__ float dppf(float v) {
    return __int_as_float(__builtin_amdgcn_update_dpp(0, __float_as_int(v), CTRL, 0xF, 0xF, true));
}
__device__ __forceinline__ float min16f(float v) {
    v = fminf(v, dppf<0xB1>(v)); v = fminf(v, dppf<0x4E>(v));
    v = fminf(v, dppf<0x124>(v)); v = fminf(v, dppf<0x128>(v));
    return v;
}
__device__ __forceinline__ float cross4minf(float v) {
    v = fminf(v, __shfl_xor(v, 16, 64)); v = fminf(v, __shfl_xor(v, 32, 64)); return v;
}
// fast fp64 reciprocal / rsqrt: fp32 seed + one fp64 Newton (~1e-14 rel err)
__device__ __forceinline__ double drcp(double d) {
    double x = (double)__builtin_amdgcn_rcpf((float)d);
    x = x * (2.0 - d * x);
    return x;
}
__device__ __forceinline__ double drsq(double d) {
    double x = (double)__builtin_amdgcn_rsqf((float)d);
    x = x * (1.5 - 0.5 * d * x * x);
    return x;
}
__device__ __forceinline__ float frcpf(float x) { return __builtin_amdgcn_rcpf(x); }

// One 64-lane wave per batch element. Lane l: q=l&15 (flow row q), r=l>>4;
// owns cells (q, 4c+r), c=0..3. Row-tail (q) and col-tail (4c+r) IP state kept
// redundantly per lane (bit-identical copies). fp64 state/residuals (robust —
// fp32 state NaN'd in rounds 4/5); fp32 only seeds Newton recips and ratio
// tests. Woodbury+Schur -> 16x16 Cholesky in registers, LDS staging for all
// gathers, early exit on mu.
__global__ __launch_bounds__(64, 1) void emd_ip_kernel(const float* __restrict__ jets1,
                                                       const float* __restrict__ jets2,
                                                       float* __restrict__ out) {
    const int l = threadIdx.x;
    const int b = blockIdx.x;
    const int q = l & 15;
    const int r = l >> 4;

    __shared__ double invDl[16 * 17];  // C[i][j] at i*17+j (stride-17 doubles: conflict-free)
    __shared__ double Sst[16 * 17];    // Schur matrix staging
    __shared__ double Lst[16 * 17];    // Lst[a*17+b] = L[b][a]
    __shared__ double GstR[16], GstI[16];  // gp rhs staging
    __shared__ double QstR[16], QstI[16];  // qc solution staging

    const float* p1 = jets1 + b * 48;
    const float* p2 = jets2 + b * 48;

    double ax = (double)p1[3 * q], ay = (double)p1[3 * q + 1];
    double px[4];
#pragma unroll
    for (int c = 0; c < 4; c++) {
        int j = 4 * c + r;
        double d0 = ((double)p2[3 * j]     - ax) + 1e-12;
        double d1 = ((double)p2[3 * j + 1] - ay) + 1e-12;
        px[c] = sqrt(d0 * d0 + d1 * d1);
    }
    double h_rt = (double)p1[3 * q + 2];
    double h_ct[4];
#pragma unroll
    for (int c = 0; c < 4; c++) h_ct[c] = (double)p2[3 * (4 * c + r) + 2];

    double sw1 = sum16d(h_rt);
    double sw2 = sum16d((double)p2[3 * q + 2]);
    const double sB = fmin(sw1, sw2);
    const double sE = fabs(sw1 - sw2);

    double x[4] = {0, 0, 0, 0}, s[4] = {1, 1, 1, 1}, z[4] = {1, 1, 1, 1};
    double yv = 0.0;
    double s_rt = 1.0, z_rt = 1.0;
    double s_ct[4] = {1, 1, 1, 1}, z_ct[4] = {1, 1, 1, 1};

    for (int it = 0; it < NITER; ++it) {
        // ---- mu = mean(s*z) over 288 (redundant copies scaled) ----
        double mub = s[0]*z[0] + s[1]*z[1] + s[2]*z[2] + s[3]*z[3]
                   + 0.25 * (s_rt * z_rt)
                   + 0.0625 * (s_ct[0]*z_ct[0] + s_ct[1]*z_ct[1] + s_ct[2]*z_ct[2] + s_ct[3]*z_ct[3]);
        double mu = sum16d(cross4d(mub)) * (1.0 / 288.0);
        if (!(mu >= 5e-7)) break;   // gap ~ 288*mu ~ 1.4e-4 << 9.6e-2; also catches NaN
        double sgmu = SIGC * mu;

        // ---- x sums ----
        double rsx = cross4d(x[0] + x[1] + x[2] + x[3]);   // row q sum
        double txs = sum16d(rsx);
        double cs[4];
#pragma unroll
        for (int c = 0; c < 4; c++) cs[c] = sum16d(x[c]);  // col 4c+r sums
        double ra = txs - sB;

        // ---- tail residuals (lane-local) ----
        double is_rt = drcp(s_rt);
        double rp_rt = rsx + s_rt - h_rt;
        double rs_rt = s_rt * z_rt - sgmu;
        double tt_rt = (z_rt * (rsx - h_rt) + sgmu) * is_rt;
        double is_ct[4], rp_ct[4], rs_ct[4], tt_ct[4];
#pragma unroll
        for (int c = 0; c < 4; c++) {
            is_ct[c] = drcp(s_ct[c]);
            rp_ct[c] = cs[c] + s_ct[c] - h_ct[c];
            rs_ct[c] = s_ct[c] * z_ct[c] - sgmu;
            tt_ct[c] = (z_ct[c] * (cs[c] - h_ct[c]) + sgmu) * is_ct[c];
        }

        // ---- cell residuals ----
        double rp[4], rs[4], iD[4], r1[4], rD1[4], is_[4];
#pragma unroll
        for (int c = 0; c < 4; c++) {
            is_[c] = drcp(s[c]);
            double rx = L2C * x[c] + px[c] + (-z[c] + z_rt + z_ct[c]) + yv;
            rp[c] = s[c] - x[c];
            rs[c] = s[c] * z[c] - sgmu;
            double tk = (sgmu - z[c] * x[c]) * is_[c];   // (z*rp - rs)/s
            iD[c] = drcp(L2C + z[c] * is_[c]);
            r1[c] = rx - tk + tt_rt + tt_ct[c];
            rD1[c] = r1[c] * iD[c];
            invDl[q * 17 + 4 * c + r] = iD[c];
        }

        // ---- sums of invD, rD1 ----
        double rsI = cross4d(iD[0] + iD[1] + iD[2] + iD[3]);
        double rsR = cross4d(rD1[0] + rD1[1] + rD1[2] + rD1[3]);
        double csI[4], csR[4];
#pragma unroll
        for (int c = 0; c < 4; c++) { csI[c] = sum16d(iD[c]); csR[c] = sum16d(rD1[c]); }

        double ar = drcp(s_rt * drcp(z_rt) + rsI);   // 1/A_q
        double aR = ar * rsR;
        double aI = ar * rsI;

        // ---- rhs gp[j] = g_c[j] - sum_i aX_i*C[i][j] (DPP row reduction) ----
        double gpR[4], gpI[4], bb[4];
#pragma unroll
        for (int c = 0; c < 4; c++) {
            gpR[c] = csR[c] - sum16d(aR * iD[c]);
            gpI[c] = csI[c] - sum16d(aI * iD[c]);
            bb[c]  = s_ct[c] * drcp(z_ct[c]) + csI[c];
            if (q == 4 * c + r) { GstR[q] = gpR[c]; GstI[q] = gpI[c]; }  // stage
        }

        // ---- Schur S[q][4c+r] = diag - sum_t ar_t C[t][q] C[t][4c+r] ----
        double accS[4] = {0, 0, 0, 0};
#pragma unroll
        for (int t = 0; t < 16; t++) {
            double w = rld(ar, t) * invDl[t * 17 + q];
#pragma unroll
            for (int c = 0; c < 4; c++) accS[c] += w * invDl[t * 17 + 4 * c + r];
        }
#pragma unroll
        for (int c = 0; c < 4; c++)
            Sst[q * 17 + 4 * c + r] = ((q == 4 * c + r) ? bb[c] : 0.0) - accS[c];

        // ---- load S row q from LDS ----
        double Sr[16];
#pragma unroll
        for (int j2 = 0; j2 < 16; j2++) Sr[j2] = Sst[q * 17 + j2];
        double D0own = Sr[q];

        // ---- 16x16 Cholesky in registers; columns staged to LDS ----
        double invdv = 0.0;
#pragma unroll
        for (int kk = 0; kk < 16; kk++) {
            double flo = fmax(1e-12 * fabs(rld(D0own, kk)), 1e-280);
            double dkk = fmax(rld(Sr[kk], kk), flo);
            double inv = drsq(dkk);
            invdv = (q == kk) ? inv : invdv;
            double Lc = Sr[kk] * inv;      // L[q][kk] (valid q>=kk)
            Sr[kk] = Lc;
            if (l < 16) Lst[kk * 17 + l] = Lc;
#pragma unroll
            for (int jj = kk + 1; jj < 16; jj++)
                Sr[jj] -= Lc * rld(Lc, jj);
        }

        // ---- gather rhs + L^T row from LDS ----
        double y1 = GstR[q], y2 = GstI[q];
        double LTr[16];
#pragma unroll
        for (int kk = 0; kk < 16; kk++) LTr[kk] = Lst[q * 17 + kk];  // L[kk][q]

        // ---- forward solve L y = gp ----
#pragma unroll
        for (int kk = 0; kk < 16; kk++) {
            double inv = rld(invdv, kk);
            double t1 = rld(y1, kk) * inv;
            double t2 = rld(y2, kk) * inv;
            if (q == kk)      { y1 = t1; y2 = t2; }
            else if (q > kk)  { y1 -= Sr[kk] * t1; y2 -= Sr[kk] * t2; }
        }
        // ---- backward solve L^T qc = y ----
#pragma unroll
        for (int kk = 15; kk >= 0; kk--) {
            double inv = rld(invdv, kk);
            double t1 = rld(y1, kk) * inv;
            double t2 = rld(y2, kk) * inv;
            if (q == kk)      { y1 = t1; y2 = t2; }
            else if (q < kk)  { y1 -= LTr[kk] * t1; y2 -= LTr[kk] * t2; }
        }
        // y1,y2 = qc[q] (identical across r-groups)

        // ---- stage qc, gather per own columns ----
        if (l < 16) { QstR[l] = y1; QstI[l] = y2; }
        double qc1c[4], qcvc[4];
#pragma unroll
        for (int c = 0; c < 4; c++) { qc1c[c] = QstR[4 * c + r]; qcvc[c] = QstI[4 * c + r]; }

        // ---- qr = ar*(g_r - sum_j C[q][j] qc_j) (cross4 reduction) ----
        double pr1 = iD[0]*qc1c[0] + iD[1]*qc1c[1] + iD[2]*qc1c[2] + iD[3]*qc1c[3];
        double prv = iD[0]*qcvc[0] + iD[1]*qcvc[1] + iD[2]*qcvc[2] + iD[3]*qcvc[3];
        double qr1 = ar * (rsR - cross4d(pr1));
        double qrv = ar * (rsI - cross4d(prv));

        // ---- u = H^{-1} r1, v = H^{-1} 1 ----
        double u[4], v[4];
#pragma unroll
        for (int c = 0; c < 4; c++) {
            u[c] = (r1[c] - qr1 - qc1c[c]) * iD[c];
            v[c] = (1.0  - qrv - qcvc[c]) * iD[c];
        }
        double usum = sum16d(cross4d(u[0] + u[1] + u[2] + u[3]));
        double vsum = sum16d(cross4d(v[0] + v[1] + v[2] + v[3]));
        double dy = (ra - usum) * drcp(vsum);

        // ---- dx + sums ----
        double dx[4];
#pragma unroll
        for (int c = 0; c < 4; c++) dx[c] = -u[c] - v[c] * dy;
        double rsdx = cross4d(dx[0] + dx[1] + dx[2] + dx[3]);
        double csdx[4];
#pragma unroll
        for (int c = 0; c < 4; c++) csdx[c] = sum16d(dx[c]);

        // ---- ds, dz (fp64); ratio tests fp32 (0.99 margin >> 3e-7 error) ----
        float am = 1e30f;
        double ds[4], dz[4];
#pragma unroll
        for (int c = 0; c < 4; c++) {
            ds[c] = dx[c] - rp[c];
            dz[c] = -(rs[c] + z[c] * ds[c]) * is_[c];
            if (ds[c] < 0.0) am = fminf(am, (float)s[c] * frcpf((float)(-ds[c])));
            if (dz[c] < 0.0) am = fminf(am, (float)z[c] * frcpf((float)(-dz[c])));
        }
        double ds_rt = -rp_rt - rsdx;
        double dz_rt = -(rs_rt + z_rt * ds_rt) * is_rt;
        if (ds_rt < 0.0) am = fminf(am, (float)s_rt * frcpf((float)(-ds_rt)));
        if (dz_rt < 0.0) am = fminf(am, (float)z_rt * frcpf((float)(-dz_rt)));
        double ds_ct[4], dz_ct[4];
#pragma unroll
        for (int c = 0; c < 4; c++) {
            ds_ct[c] = -rp_ct[c] - csdx[c];
            dz_ct[c] = -(rs_ct[c] + z_ct[c] * ds_ct[c]) * is_ct[c];
            if (ds_ct[c] < 0.0) am = fminf(am, (float)s_ct[c] * frcpf((float)(-ds_ct[c])));
            if (dz_ct[c] < 0.0) am = fminf(am, (float)z_ct[c] * frcpf((float)(-dz_ct[c])));
        }
        float amin = min16f(cross4minf(am));
        double alpha = 0.99 * fmin(1.0, (double)amin);
        alpha = ((dy - dy) == 0.0) ? alpha : 0.0;   // freeze on garbage direction

        // ---- step ----
#pragma unroll
        for (int c = 0; c < 4; c++) {
            x[c] += alpha * dx[c];
            s[c] += alpha * ds[c];
            z[c] += alpha * dz[c];
            s_ct[c] += alpha * ds_ct[c];
            z_ct[c] += alpha * dz_ct[c];
        }
        yv += alpha * dy;
        s_rt += alpha * ds_rt;
        z_rt += alpha * dz_rt;
    }

    // ---- emd = p.x + |sum w1 - sum w2| ----
    double e = sum16d(cross4d(px[0]*x[0] + px[1]*x[1] + px[2]*x[2] + px[3]*x[3]));
    if (l == 0) out[b] = (float)(e + sE);
}

extern "C" void kernel_launch(void* const* d_in, const int* in_sizes, int n_in,
                              void* d_out, int out_size, void* d_ws, size_t ws_size,
                              hipStream_t stream) {
    const float* jets1 = (const float*)d_in[0];
    const float* jets2 = (const float*)d_in[1];
    float* out = (float*)d_out;
    int B = in_sizes[0] / 48;   // 32
    emd_ip_kernel<<<dim3(B), dim3(64), 0, stream>>>(jets1, jets2, out);
}